// Round 15
// baseline (47.452 us; speedup 1.0000x reference)
//
#include <hip/hip_runtime.h>
#include <hip/hip_bf16.h>
#include <math.h>

#define DIM   256
#define NHEAD 8
#define HD    32
#define NTOK  4096
#define GRD   64
#define BATCH 2
#define MTOT  (BATCH * NTOK)   // 8192
#define PLANE (NTOK * HD)      // 131072 elems per (sel,b,h) plane

typedef __attribute__((ext_vector_type(8))) short bf16x8;
typedef __attribute__((ext_vector_type(4))) float f32x4;

static __device__ __forceinline__ unsigned short f2b(float f) {
  __hip_bfloat16 h = __float2bfloat16(f);
  union { __hip_bfloat16 h; unsigned short u; } cv;
  cv.h = h;
  return cv.u;
}

static __device__ __forceinline__ float exp2g(float x) {
  return __builtin_amdgcn_exp2f(x);   // v_exp_f32 (2^x)
}

static __device__ __forceinline__ unsigned cvtpk_bf16(float lo, float hi) {
  unsigned r;
  asm("v_cvt_pk_bf16_f32 %0, %1, %2" : "=v"(r) : "v"(lo), "v"(hi));
  return r;
}

static __device__ __forceinline__ bf16x8 pack8(float4 a0, float4 a1) {
  union { bf16x8 v; unsigned short u[8]; } o;
  o.u[0] = f2b(a0.x); o.u[1] = f2b(a0.y); o.u[2] = f2b(a0.z); o.u[3] = f2b(a0.w);
  o.u[4] = f2b(a1.x); o.u[5] = f2b(a1.y); o.u[6] = f2b(a1.z); o.u[7] = f2b(a1.w);
  return o.v;
}

#define GLDS16(SRC, DST) __builtin_amdgcn_global_load_lds( \
    (const __attribute__((address_space(1))) void*)(SRC),  \
    (__attribute__((address_space(3))) void*)(DST), 16, 0, 0)

// ---------------- GEMM1: qkv = x(fp32) @ Wqkv(fp32)^T -> bf16 planes --------
// 128x128 tile, BK=64 (4 K-iters, 8 barriers). Q/K blocks (bx<4): scatter
// [tok][32] planes. V blocks (bx>=4): LDS-transpose -> V^T [32 d][4096 tok].
__global__ __launch_bounds__(256) void gemm_qkv(const float* __restrict__ A,
                                                const float* __restrict__ Bw,
                                                unsigned short* __restrict__ Cout) {
  const int K = 256;
  __shared__ __align__(16) char smem[73728];
  __hip_bfloat16* As = (__hip_bfloat16*)smem;            // [128*72]
  __hip_bfloat16* Bs = (__hip_bfloat16*)(smem + 36864);  // [128*72]
  const int tid = threadIdx.x;
  const int l = tid & 63, w = tid >> 6;
  const int bm = blockIdx.y * 128, bn = blockIdx.x * 128;
  const int wr = w >> 1, wc = w & 1;
  const int lr = l & 15, kh = l >> 4;

  f32x4 acc[4][4];
  #pragma unroll
  for (int i = 0; i < 4; ++i)
    #pragma unroll
    for (int j = 0; j < 4; ++j)
      acc[i][j] = (f32x4){0.f, 0.f, 0.f, 0.f};

  for (int k0 = 0; k0 < K; k0 += 64) {
    #pragma unroll
    for (int i = 0; i < 4; ++i) {
      const int ch = i * 256 + tid;
      const int row = ch >> 3, col = (ch & 7) * 8;
      const float* ga = A  + (size_t)(bm + row) * K + k0 + col;
      const float* gb = Bw + (size_t)(bn + row) * K + k0 + col;
      float4 a0 = *(const float4*)ga, a1 = *(const float4*)(ga + 4);
      float4 b0 = *(const float4*)gb, b1 = *(const float4*)(gb + 4);
      *(bf16x8*)&As[row * 72 + col] = pack8(a0, a1);
      *(bf16x8*)&Bs[row * 72 + col] = pack8(b0, b1);
    }
    __syncthreads();

    #pragma unroll
    for (int ks = 0; ks < 2; ++ks) {
      bf16x8 af[4], bfr[4];
      #pragma unroll
      for (int f = 0; f < 4; ++f) {
        af[f]  = *(const bf16x8*)&As[(wr * 64 + f * 16 + lr) * 72 + ks * 32 + kh * 8];
        bfr[f] = *(const bf16x8*)&Bs[(wc * 64 + f * 16 + lr) * 72 + ks * 32 + kh * 8];
      }
      #pragma unroll
      for (int fi = 0; fi < 4; ++fi)
        #pragma unroll
        for (int fj = 0; fj < 4; ++fj)
          acc[fi][fj] = __builtin_amdgcn_mfma_f32_16x16x32_bf16(af[fi], bfr[fj], acc[fi][fj], 0, 0, 0);
    }
    __syncthreads();
  }

  if (blockIdx.x < 4) {
    // Q/K planes: plane = sel*16 + bb*8 + hh, layout [tok][32]
    #pragma unroll
    for (int fi = 0; fi < 4; ++fi)
      #pragma unroll
      for (int fj = 0; fj < 4; ++fj)
        #pragma unroll
        for (int rr = 0; rr < 4; ++rr) {
          const int m = bm + wr * 64 + fi * 16 + kh * 4 + rr;
          const int n = bn + wc * 64 + fj * 16 + lr;
          const int sel = n >> 8, rem = n & 255;
          const int hh = rem >> 5, d = rem & 31;
          const int bb = m >> 12, tok = m & 4095;
          Cout[(size_t)(sel * 16 + bb * 8 + hh) * PLANE + tok * 32 + d] =
              f2b(acc[fi][fj][rr]);
        }
  } else {
    // V blocks: transpose through LDS, write V^T [d][tok] coalesced.
    unsigned short* Ts = (unsigned short*)smem;   // [128][136]
    #pragma unroll
    for (int fi = 0; fi < 4; ++fi)
      #pragma unroll
      for (int fj = 0; fj < 4; ++fj)
        #pragma unroll
        for (int rr = 0; rr < 4; ++rr) {
          const int tokl = wr * 64 + fi * 16 + kh * 4 + rr;
          const int dl   = wc * 64 + fj * 16 + lr;
          Ts[tokl * 136 + dl] = f2b(acc[fi][fj][rr]);
        }
    __syncthreads();
    const int dl = tid >> 1, th = (tid & 1) * 64;
    const int dg = (bn - 512) + dl;          // 0..255
    const int hh = dg >> 5, dd = dg & 31;
    const int bb = bm >> 12, tokb = bm & 4095;
    unsigned short* vt = Cout + (size_t)(32 + bb * 8 + hh) * PLANE + dd * 4096 + tokb + th;
    #pragma unroll
    for (int j = 0; j < 8; ++j) {
      union { bf16x8 v; unsigned short u[8]; } o;
      #pragma unroll
      for (int e = 0; e < 8; ++e)
        o.u[e] = Ts[(th + j * 8 + e) * 136 + dl];
      *(bf16x8*)(vt + j * 8) = o.v;
    }
  }
}

// ---------------- GEMM2: out = attn(bf16) @ Wproj(fp32)^T + bias (fp32) -----
// 64x128 tile -> grid (2, 128) = 256 blocks (full GPU; R7/R12-measured).
__global__ __launch_bounds__(256) void gemm_proj(const __hip_bfloat16* __restrict__ A,
                                                 const float* __restrict__ Bw,
                                                 const float* __restrict__ bias,
                                                 float* __restrict__ Cout) {
  const int K = 256, N = 256;
  __shared__ __hip_bfloat16 As[64 * 32];    // linear: global_load_lds dest
  __shared__ __hip_bfloat16 Bs[128 * 40];   // padded: reg-staged
  const int tid = threadIdx.x;
  const int l = tid & 63, w = tid >> 6;
  const int bm = blockIdx.y * 64, bn = blockIdx.x * 128;
  const int wr = w >> 1, wc = w & 1;
  const int lr = l & 15, kh = l >> 4;
  const int lrow = tid >> 2, lcol = (tid & 3) * 8;

  f32x4 acc[2][4];
  #pragma unroll
  for (int i = 0; i < 2; ++i)
    #pragma unroll
    for (int j = 0; j < 4; ++j)
      acc[i][j] = (f32x4){0.f, 0.f, 0.f, 0.f};

  for (int k0 = 0; k0 < K; k0 += 32) {
    {
      const __hip_bfloat16* ga = A + (size_t)(bm + lrow) * K + k0 + lcol;
      GLDS16(ga, &As[w * 512]);
    }
    #pragma unroll
    for (int i = 0; i < 2; ++i) {
      const int row = i * 64 + lrow;
      const float* gb = Bw + (size_t)(bn + row) * K + k0 + lcol;
      float4 b0 = *(const float4*)gb, b1 = *(const float4*)(gb + 4);
      *(bf16x8*)&Bs[row * 40 + lcol] = pack8(b0, b1);
    }
    __syncthreads();

    bf16x8 af[2], bfr[4];
    #pragma unroll
    for (int f = 0; f < 2; ++f)
      af[f] = *(const bf16x8*)&As[(wr * 32 + f * 16 + lr) * 32 + kh * 8];
    #pragma unroll
    for (int f = 0; f < 4; ++f)
      bfr[f] = *(const bf16x8*)&Bs[(wc * 64 + f * 16 + lr) * 40 + kh * 8];
    #pragma unroll
    for (int fi = 0; fi < 2; ++fi)
      #pragma unroll
      for (int fj = 0; fj < 4; ++fj)
        acc[fi][fj] = __builtin_amdgcn_mfma_f32_16x16x32_bf16(af[fi], bfr[fj], acc[fi][fj], 0, 0, 0);
    __syncthreads();
  }

  #pragma unroll
  for (int fi = 0; fi < 2; ++fi)
    #pragma unroll
    for (int fj = 0; fj < 4; ++fj)
      #pragma unroll
      for (int rr = 0; rr < 4; ++rr) {
        const int m = bm + wr * 32 + fi * 16 + kh * 4 + rr;
        const int n = bn + wc * 64 + fj * 16 + lr;
        Cout[(size_t)m * N + n] = acc[fi][fj][rr] + bias[n];
      }
}

// ---------------- MFMA flash-band attention, banded-tile skipping -----------
// R14 structure + wave-uniform tile culling: wave wq's valid keys span
// [wq*16-3, wq*16+18] -> S-tiles kt in {wq-1, wq, wq+1} only; PV half-pass
// hf0 (keys 0-31) only for wq<=2, hf1 (keys 32-63) only for wq>=1. Skipped
// tiles are provably fully masked; their pkw words are 0.
__global__ __launch_bounds__(512, 4) void local_attn_mfma(
    const unsigned short* __restrict__ qkv, const float* __restrict__ temp,
    unsigned short* __restrict__ attn_out) {
  __shared__ __align__(16) unsigned short Ks[512 * 32];   // 32768 B
  __shared__ __align__(16) unsigned short Vt[32 * 512];   // 32768 B

  const int P = blockIdx.x;
  const int L = (P & 7) * 64 + (P >> 3);    // XCD-chunked remap (512 = 8*64)
  const int plane = L >> 5, rp = L & 31;
  const int b = plane >> 3, h = plane & 7;
  const int tid = threadIdx.x;
  const int l = tid & 63, wv = tid >> 6;
  const int qr = wv >> 2, wq = wv & 3;
  const int q15 = l & 15, sg = l >> 4;
  const int r = rp * 2 + qr;                // this wave's query grid-row

  // log2-domain scale: softmax(x*s) == softmax2(x*s*log2e)
  const float scale2 = 0.17677669529663687f * 1.44269504088896f * temp[0];

  const unsigned short* qplane  = qkv + (size_t)(b * 8 + h) * PLANE;
  const unsigned short* kplane  = qplane + (size_t)16 * PLANE;
  const unsigned short* vtplane = qplane + (size_t)32 * PLANE;

  const int rbase = rp * 2 - 3;

  // ---- stage K: 512 band-tokens x 64B rows (2048 16B chunks) ---------------
  #pragma unroll
  for (int i = 0; i < 4; ++i) {
    const int ch = i * 512 + tid;
    const int tok = ch >> 2, jjp = ch & 3;
    const int ri = tok >> 6, kloc = tok & 63;
    int row = rbase + ri; row = row < 0 ? 0 : (row > 63 ? 63 : row);
    const int jl = jjp ^ ((tok >> 1) & 3);
    const unsigned short* src = kplane + (size_t)(row * 64 + kloc) * 32 + jl * 8;
    GLDS16(src, &Ks[(i * 512 + (tid & ~63)) * 8]);
  }
  // ---- stage V^T: 32 d-rows x 512 tokens (2048 16B chunks) -----------------
  #pragma unroll
  for (int i = 0; i < 4; ++i) {
    const int ch = i * 512 + tid;
    const int d = ch >> 6, chp = ch & 63;
    const int chl = chp ^ (d & 7);
    const int ri = chl >> 3, part = chl & 7;
    int row = rbase + ri; row = row < 0 ? 0 : (row > 63 ? 63 : row);
    const unsigned short* src = vtplane + (size_t)d * 4096 + row * 64 + part * 8;
    GLDS16(src, &Vt[(i * 512 + (tid & ~63)) * 8]);
  }

  // ---- Q fragment (B-operand style): Q[q15][sg*8..+8] ----------------------
  const bf16x8 qf = *(const bf16x8*)(qplane + (size_t)(r * 64 + wq * 16 + q15) * 32 + sg * 8);

  __syncthreads();

  const int qcol = wq * 16 + q15;
  const int ktlo = (wq == 0) ? 0 : wq - 1;     // wave-uniform tile window
  const int kthi = (wq == 3) ? 3 : wq + 1;
  const bool needhf0 = (wq <= 2);
  const bool needhf1 = (wq >= 1);

  float m_run = -INFINITY, l_run = 0.f;
  f32x4 Od[2];
  Od[0] = (f32x4){0.f, 0.f, 0.f, 0.f};
  Od[1] = (f32x4){0.f, 0.f, 0.f, 0.f};
  const f32x4 zf = {0.f, 0.f, 0.f, 0.f};
  const int laA = ((l >> 4) & 1) * 32 + q15;   // source lane for P-frag low keys
  const int laB = laA + 16;
  const bool hiG = (l & 32) != 0;              // group>=2 -> use kt 2h+1

  #pragma unroll
  for (int c = 0; c < 7; ++c) {
    const int rr_c = r - 3 + c;                // wave-uniform
    if (rr_c >= 0 && rr_c <= 63) {
      const int bri = c + qr;                  // staged band-row index
      // ---- QK^T: only tiles kt in [ktlo, kthi] ----------------------------
      f32x4 st[4];
      __builtin_amdgcn_s_setprio(1);
      #pragma unroll
      for (int kt = 0; kt < 4; ++kt) {
        if (kt >= ktlo && kt <= kthi) {
          const int tok = bri * 64 + kt * 16 + q15;
          const bf16x8 kf = *(const bf16x8*)((const char*)Ks + tok * 64 +
                                             ((sg ^ ((tok >> 1) & 3)) << 4));
          st[kt] = __builtin_amdgcn_mfma_f32_16x16x32_bf16(kf, qf, zf, 0, 0, 0);
        }
      }
      __builtin_amdgcn_s_setprio(0);
      // ---- mask + scale(log2) + chunk max ---------------------------------
      float mc = -INFINITY;
      #pragma unroll
      for (int kt = 0; kt < 4; ++kt) {
        if (kt >= ktlo && kt <= kthi) {
          #pragma unroll
          for (int rg = 0; rg < 4; ++rg) {
            const int keyloc = kt * 16 + sg * 4 + rg;
            const bool ok = (unsigned)(keyloc - qcol + 3) <= 6u;
            const float v = ok ? st[kt][rg] * scale2 : -INFINITY;
            st[kt][rg] = v;
            mc = fmaxf(mc, v);
          }
        }
      }
      mc = fmaxf(mc, __shfl_xor(mc, 16));
      mc = fmaxf(mc, __shfl_xor(mc, 32));
      const float mnew = fmaxf(m_run, mc);
      const float alpha = exp2g(m_run - mnew);   // 0 on first chunk
      float lc = 0.f;
      #pragma unroll
      for (int kt = 0; kt < 4; ++kt) {
        if (kt >= ktlo && kt <= kthi) {
          #pragma unroll
          for (int rg = 0; rg < 4; ++rg) {
            const float e = exp2g(st[kt][rg] - mnew);   // masked -> 0
            st[kt][rg] = e;
            lc += e;
          }
        }
      }
      lc += __shfl_xor(lc, 16);
      lc += __shfl_xor(lc, 32);
      l_run = l_run * alpha + lc;
      m_run = mnew;
      Od[0] *= alpha;
      Od[1] *= alpha;

      // ---- pack p to bf16 pairs (skipped tiles -> 0), exchange, PV --------
      unsigned pkw[8];
      #pragma unroll
      for (int kt = 0; kt < 4; ++kt) {
        if (kt >= ktlo && kt <= kthi) {
          pkw[kt * 2 + 0] = cvtpk_bf16(st[kt][0], st[kt][1]);
          pkw[kt * 2 + 1] = cvtpk_bf16(st[kt][2], st[kt][3]);
        } else {
          pkw[kt * 2 + 0] = 0u;
          pkw[kt * 2 + 1] = 0u;
        }
      }
      #pragma unroll
      for (int hf = 0; hf < 2; ++hf) {
        const bool needhf = (hf == 0) ? needhf0 : needhf1;
        if (needhf) {
          unsigned wA[2], wB[2];
          #pragma unroll
          for (int w2 = 0; w2 < 2; ++w2) {
            const unsigned a0 = (unsigned)__shfl((int)pkw[(2 * hf) * 2 + w2], laA);
            const unsigned a1 = (unsigned)__shfl((int)pkw[(2 * hf + 1) * 2 + w2], laA);
            wA[w2] = hiG ? a1 : a0;
            const unsigned b0 = (unsigned)__shfl((int)pkw[(2 * hf) * 2 + w2], laB);
            const unsigned b1 = (unsigned)__shfl((int)pkw[(2 * hf + 1) * 2 + w2], laB);
            wB[w2] = hiG ? b1 : b0;
          }
          union { unsigned u[4]; bf16x8 v; } pf;
          pf.u[0] = wA[0]; pf.u[1] = wA[1]; pf.u[2] = wB[0]; pf.u[3] = wB[1];
          __builtin_amdgcn_s_setprio(1);
          #pragma unroll
          for (int dt = 0; dt < 2; ++dt) {
            const int d = dt * 16 + q15;
            const int chl = bri * 8 + hf * 4 + sg;
            const bf16x8 vf = *(const bf16x8*)((const char*)Vt + d * 1024 +
                                               ((chl ^ (d & 7)) << 4));
            Od[dt] = __builtin_amdgcn_mfma_f32_16x16x32_bf16(vf, pf.v, Od[dt], 0, 0, 0);
          }
          __builtin_amdgcn_s_setprio(0);
        }
      }
    }
  }

  // ---- normalize + store O^T (lane: d = dt*16+sg*4+rg, q = q15) ------------
  const float invl = 1.0f / l_run;
  #pragma unroll
  for (int dt = 0; dt < 2; ++dt) {
    const unsigned w0 = cvtpk_bf16(Od[dt][0] * invl, Od[dt][1] * invl);
    const unsigned w1 = cvtpk_bf16(Od[dt][2] * invl, Od[dt][3] * invl);
    unsigned short* dst = attn_out + (size_t)(b * 4096 + r * 64 + qcol) * 256 +
                          h * 32 + dt * 16 + sg * 4;
    uint2 uu; uu.x = w0; uu.y = w1;
    *(uint2*)dst = uu;
  }
}

extern "C" void kernel_launch(void* const* d_in, const int* in_sizes, int n_in,
                              void* d_out, int out_size, void* d_ws, size_t ws_size,
                              hipStream_t stream) {
  const float* x     = (const float*)d_in[0];
  const float* Wqkv  = (const float*)d_in[1];
  const float* Wproj = (const float*)d_in[2];
  const float* bproj = (const float*)d_in[3];
  const float* temp  = (const float*)d_in[4];
  float* out = (float*)d_out;

  // workspace layout (bytes):
  //   [0, 12582912)            qkv bf16 planes: 48 x 131072 elems
  //                            (Q/K planes [tok][32]; V planes transposed [32][4096])
  //   [25165824, 29360128)     attn_bf16 [8192][256]
  char* ws = (char*)d_ws;
  unsigned short* qkv_bf  = (unsigned short*)ws;
  __hip_bfloat16* attn_bf = (__hip_bfloat16*)(ws + 25165824);

  // 1) qkv = x @ Wqkv^T (fused fp32->bf16), Q/K planar + V transposed
  {
    dim3 grid(3 * DIM / 128, MTOT / 128);   // (6, 64)
    gemm_qkv<<<grid, 256, 0, stream>>>(x, Wqkv, qkv_bf);
  }
  // 2) MFMA flash-band attention (2 query-rows/block) -> attn_bf
  local_attn_mfma<<<BATCH * NHEAD * (GRD / 2), 512, 0, stream>>>(
      qkv_bf, temp, (unsigned short*)attn_bf);
  // 3) out = attn @ Wproj^T + bias
  {
    dim3 grid(DIM / 128, MTOT / 64);        // (2, 128) = 256 blocks
    gemm_proj<<<grid, 256, 0, stream>>>(attn_bf, Wproj, bproj, out);
  }
}

// Round 16
// 45.284 us; speedup vs baseline: 1.0479x; 1.0479x over previous
//
#include <hip/hip_runtime.h>
#include <hip/hip_bf16.h>
#include <math.h>

#define DIM   256
#define NHEAD 8
#define HD    32
#define NTOK  4096
#define GRD   64
#define BATCH 2
#define MTOT  (BATCH * NTOK)   // 8192
#define PLANE (NTOK * HD)      // 131072 elems per (sel,b,h) plane

typedef __attribute__((ext_vector_type(8))) short bf16x8;
typedef __attribute__((ext_vector_type(4))) float f32x4;

static __device__ __forceinline__ unsigned short f2b(float f) {
  __hip_bfloat16 h = __float2bfloat16(f);
  union { __hip_bfloat16 h; unsigned short u; } cv;
  cv.h = h;
  return cv.u;
}

static __device__ __forceinline__ float exp2g(float x) {
  return __builtin_amdgcn_exp2f(x);   // v_exp_f32 (2^x)
}

static __device__ __forceinline__ unsigned cvtpk_bf16(float lo, float hi) {
  unsigned r;
  asm("v_cvt_pk_bf16_f32 %0, %1, %2" : "=v"(r) : "v"(lo), "v"(hi));
  return r;
}

static __device__ __forceinline__ bf16x8 pack8(float4 a0, float4 a1) {
  union { bf16x8 v; unsigned short u[8]; } o;
  o.u[0] = f2b(a0.x); o.u[1] = f2b(a0.y); o.u[2] = f2b(a0.z); o.u[3] = f2b(a0.w);
  o.u[4] = f2b(a1.x); o.u[5] = f2b(a1.y); o.u[6] = f2b(a1.z); o.u[7] = f2b(a1.w);
  return o.v;
}

#define GLDS16(SRC, DST) __builtin_amdgcn_global_load_lds( \
    (const __attribute__((address_space(1))) void*)(SRC),  \
    (__attribute__((address_space(3))) void*)(DST), 16, 0, 0)

// ---------------- GEMM1: qkv = x(fp32) @ Wqkv(fp32)^T -> bf16 planes --------
// 128x128 tile, BK=64 (4 K-iters, 8 barriers). Q/K blocks (bx<4): scatter
// [tok][32] planes. V blocks (bx>=4): LDS-transpose -> V^T [32 d][4096 tok].
__global__ __launch_bounds__(256) void gemm_qkv(const float* __restrict__ A,
                                                const float* __restrict__ Bw,
                                                unsigned short* __restrict__ Cout) {
  const int K = 256;
  __shared__ __align__(16) char smem[73728];
  __hip_bfloat16* As = (__hip_bfloat16*)smem;            // [128*72]
  __hip_bfloat16* Bs = (__hip_bfloat16*)(smem + 36864);  // [128*72]
  const int tid = threadIdx.x;
  const int l = tid & 63, w = tid >> 6;
  const int bm = blockIdx.y * 128, bn = blockIdx.x * 128;
  const int wr = w >> 1, wc = w & 1;
  const int lr = l & 15, kh = l >> 4;

  f32x4 acc[4][4];
  #pragma unroll
  for (int i = 0; i < 4; ++i)
    #pragma unroll
    for (int j = 0; j < 4; ++j)
      acc[i][j] = (f32x4){0.f, 0.f, 0.f, 0.f};

  for (int k0 = 0; k0 < K; k0 += 64) {
    #pragma unroll
    for (int i = 0; i < 4; ++i) {
      const int ch = i * 256 + tid;
      const int row = ch >> 3, col = (ch & 7) * 8;
      const float* ga = A  + (size_t)(bm + row) * K + k0 + col;
      const float* gb = Bw + (size_t)(bn + row) * K + k0 + col;
      float4 a0 = *(const float4*)ga, a1 = *(const float4*)(ga + 4);
      float4 b0 = *(const float4*)gb, b1 = *(const float4*)(gb + 4);
      *(bf16x8*)&As[row * 72 + col] = pack8(a0, a1);
      *(bf16x8*)&Bs[row * 72 + col] = pack8(b0, b1);
    }
    __syncthreads();

    #pragma unroll
    for (int ks = 0; ks < 2; ++ks) {
      bf16x8 af[4], bfr[4];
      #pragma unroll
      for (int f = 0; f < 4; ++f) {
        af[f]  = *(const bf16x8*)&As[(wr * 64 + f * 16 + lr) * 72 + ks * 32 + kh * 8];
        bfr[f] = *(const bf16x8*)&Bs[(wc * 64 + f * 16 + lr) * 72 + ks * 32 + kh * 8];
      }
      #pragma unroll
      for (int fi = 0; fi < 4; ++fi)
        #pragma unroll
        for (int fj = 0; fj < 4; ++fj)
          acc[fi][fj] = __builtin_amdgcn_mfma_f32_16x16x32_bf16(af[fi], bfr[fj], acc[fi][fj], 0, 0, 0);
    }
    __syncthreads();
  }

  if (blockIdx.x < 4) {
    // Q/K planes: plane = sel*16 + bb*8 + hh, layout [tok][32]
    #pragma unroll
    for (int fi = 0; fi < 4; ++fi)
      #pragma unroll
      for (int fj = 0; fj < 4; ++fj)
        #pragma unroll
        for (int rr = 0; rr < 4; ++rr) {
          const int m = bm + wr * 64 + fi * 16 + kh * 4 + rr;
          const int n = bn + wc * 64 + fj * 16 + lr;
          const int sel = n >> 8, rem = n & 255;
          const int hh = rem >> 5, d = rem & 31;
          const int bb = m >> 12, tok = m & 4095;
          Cout[(size_t)(sel * 16 + bb * 8 + hh) * PLANE + tok * 32 + d] =
              f2b(acc[fi][fj][rr]);
        }
  } else {
    // V blocks: transpose through LDS, write V^T [d][tok] coalesced.
    unsigned short* Ts = (unsigned short*)smem;   // [128][136]
    #pragma unroll
    for (int fi = 0; fi < 4; ++fi)
      #pragma unroll
      for (int fj = 0; fj < 4; ++fj)
        #pragma unroll
        for (int rr = 0; rr < 4; ++rr) {
          const int tokl = wr * 64 + fi * 16 + kh * 4 + rr;
          const int dl   = wc * 64 + fj * 16 + lr;
          Ts[tokl * 136 + dl] = f2b(acc[fi][fj][rr]);
        }
    __syncthreads();
    const int dl = tid >> 1, th = (tid & 1) * 64;
    const int dg = (bn - 512) + dl;          // 0..255
    const int hh = dg >> 5, dd = dg & 31;
    const int bb = bm >> 12, tokb = bm & 4095;
    unsigned short* vt = Cout + (size_t)(32 + bb * 8 + hh) * PLANE + dd * 4096 + tokb + th;
    #pragma unroll
    for (int j = 0; j < 8; ++j) {
      union { bf16x8 v; unsigned short u[8]; } o;
      #pragma unroll
      for (int e = 0; e < 8; ++e)
        o.u[e] = Ts[(th + j * 8 + e) * 136 + dl];
      *(bf16x8*)(vt + j * 8) = o.v;
    }
  }
}

// ---------------- GEMM2: out = attn(bf16) @ Wproj(fp32)^T + bias (fp32) -----
// 64x128 tile -> grid (2, 128) = 256 blocks (full GPU; R7/R12-measured).
__global__ __launch_bounds__(256) void gemm_proj(const __hip_bfloat16* __restrict__ A,
                                                 const float* __restrict__ Bw,
                                                 const float* __restrict__ bias,
                                                 float* __restrict__ Cout) {
  const int K = 256, N = 256;
  __shared__ __hip_bfloat16 As[64 * 32];    // linear: global_load_lds dest
  __shared__ __hip_bfloat16 Bs[128 * 40];   // padded: reg-staged
  const int tid = threadIdx.x;
  const int l = tid & 63, w = tid >> 6;
  const int bm = blockIdx.y * 64, bn = blockIdx.x * 128;
  const int wr = w >> 1, wc = w & 1;
  const int lr = l & 15, kh = l >> 4;
  const int lrow = tid >> 2, lcol = (tid & 3) * 8;

  f32x4 acc[2][4];
  #pragma unroll
  for (int i = 0; i < 2; ++i)
    #pragma unroll
    for (int j = 0; j < 4; ++j)
      acc[i][j] = (f32x4){0.f, 0.f, 0.f, 0.f};

  for (int k0 = 0; k0 < K; k0 += 32) {
    {
      const __hip_bfloat16* ga = A + (size_t)(bm + lrow) * K + k0 + lcol;
      GLDS16(ga, &As[w * 512]);
    }
    #pragma unroll
    for (int i = 0; i < 2; ++i) {
      const int row = i * 64 + lrow;
      const float* gb = Bw + (size_t)(bn + row) * K + k0 + lcol;
      float4 b0 = *(const float4*)gb, b1 = *(const float4*)(gb + 4);
      *(bf16x8*)&Bs[row * 40 + lcol] = pack8(b0, b1);
    }
    __syncthreads();

    bf16x8 af[2], bfr[4];
    #pragma unroll
    for (int f = 0; f < 2; ++f)
      af[f] = *(const bf16x8*)&As[(wr * 32 + f * 16 + lr) * 32 + kh * 8];
    #pragma unroll
    for (int f = 0; f < 4; ++f)
      bfr[f] = *(const bf16x8*)&Bs[(wc * 64 + f * 16 + lr) * 40 + kh * 8];
    #pragma unroll
    for (int fi = 0; fi < 2; ++fi)
      #pragma unroll
      for (int fj = 0; fj < 4; ++fj)
        acc[fi][fj] = __builtin_amdgcn_mfma_f32_16x16x32_bf16(af[fi], bfr[fj], acc[fi][fj], 0, 0, 0);
    __syncthreads();
  }

  #pragma unroll
  for (int fi = 0; fi < 2; ++fi)
    #pragma unroll
    for (int fj = 0; fj < 4; ++fj)
      #pragma unroll
      for (int rr = 0; rr < 4; ++rr) {
        const int m = bm + wr * 32 + fi * 16 + kh * 4 + rr;
        const int n = bn + wc * 64 + fj * 16 + lr;
        Cout[(size_t)m * N + n] = acc[fi][fj][rr] + bias[n];
      }
}

// ---------------- MFMA flash-band attention, 2 query-rows per block ---------
// (R12-verified structure + exp2-domain softmax + setprio around MFMA.)
__global__ __launch_bounds__(512, 4) void local_attn_mfma(
    const unsigned short* __restrict__ qkv, const float* __restrict__ temp,
    unsigned short* __restrict__ attn_out) {
  __shared__ __align__(16) unsigned short Ks[512 * 32];   // 32768 B
  __shared__ __align__(16) unsigned short Vt[32 * 512];   // 32768 B

  const int P = blockIdx.x;
  const int L = (P & 7) * 64 + (P >> 3);    // XCD-chunked remap (512 = 8*64)
  const int plane = L >> 5, rp = L & 31;
  const int b = plane >> 3, h = plane & 7;
  const int tid = threadIdx.x;
  const int l = tid & 63, wv = tid >> 6;
  const int qr = wv >> 2, wq = wv & 3;
  const int q15 = l & 15, sg = l >> 4;
  const int r = rp * 2 + qr;                // this wave's query grid-row

  // log2-domain scale: softmax(x*s) == softmax2(x*s*log2e)
  const float scale2 = 0.17677669529663687f * 1.44269504088896f * temp[0];

  const unsigned short* qplane  = qkv + (size_t)(b * 8 + h) * PLANE;
  const unsigned short* kplane  = qplane + (size_t)16 * PLANE;
  const unsigned short* vtplane = qplane + (size_t)32 * PLANE;

  const int rbase = rp * 2 - 3;

  // ---- stage K: 512 band-tokens x 64B rows (2048 16B chunks) ---------------
  #pragma unroll
  for (int i = 0; i < 4; ++i) {
    const int ch = i * 512 + tid;
    const int tok = ch >> 2, jjp = ch & 3;
    const int ri = tok >> 6, kloc = tok & 63;
    int row = rbase + ri; row = row < 0 ? 0 : (row > 63 ? 63 : row);
    const int jl = jjp ^ ((tok >> 1) & 3);
    const unsigned short* src = kplane + (size_t)(row * 64 + kloc) * 32 + jl * 8;
    GLDS16(src, &Ks[(i * 512 + (tid & ~63)) * 8]);
  }
  // ---- stage V^T: 32 d-rows x 512 tokens (2048 16B chunks) -----------------
  #pragma unroll
  for (int i = 0; i < 4; ++i) {
    const int ch = i * 512 + tid;
    const int d = ch >> 6, chp = ch & 63;
    const int chl = chp ^ (d & 7);
    const int ri = chl >> 3, part = chl & 7;
    int row = rbase + ri; row = row < 0 ? 0 : (row > 63 ? 63 : row);
    const unsigned short* src = vtplane + (size_t)d * 4096 + row * 64 + part * 8;
    GLDS16(src, &Vt[(i * 512 + (tid & ~63)) * 8]);
  }

  // ---- Q fragment (B-operand style): Q[q15][sg*8..+8] ----------------------
  const bf16x8 qf = *(const bf16x8*)(qplane + (size_t)(r * 64 + wq * 16 + q15) * 32 + sg * 8);

  __syncthreads();

  const int qcol = wq * 16 + q15;
  float m_run = -INFINITY, l_run = 0.f;
  f32x4 Od[2];
  Od[0] = (f32x4){0.f, 0.f, 0.f, 0.f};
  Od[1] = (f32x4){0.f, 0.f, 0.f, 0.f};
  const f32x4 zf = {0.f, 0.f, 0.f, 0.f};
  const int laA = ((l >> 4) & 1) * 32 + q15;   // source lane for P-frag low keys
  const int laB = laA + 16;
  const bool hiG = (l & 32) != 0;              // group>=2 -> use kt 2h+1

  #pragma unroll
  for (int c = 0; c < 7; ++c) {
    const int rr_c = r - 3 + c;                // wave-uniform
    if (rr_c >= 0 && rr_c <= 63) {
      const int bri = c + qr;                  // staged band-row index 0..8
      // ---- QK^T: 4 S^T tiles ----------------------------------------------
      f32x4 st[4];
      __builtin_amdgcn_s_setprio(1);
      #pragma unroll
      for (int kt = 0; kt < 4; ++kt) {
        const int tok = bri * 64 + kt * 16 + q15;
        const bf16x8 kf = *(const bf16x8*)((const char*)Ks + tok * 64 +
                                           ((sg ^ ((tok >> 1) & 3)) << 4));
        st[kt] = __builtin_amdgcn_mfma_f32_16x16x32_bf16(kf, qf, zf, 0, 0, 0);
      }
      __builtin_amdgcn_s_setprio(0);
      // ---- mask + scale(log2) + chunk max ---------------------------------
      float mc = -INFINITY;
      #pragma unroll
      for (int kt = 0; kt < 4; ++kt)
        #pragma unroll
        for (int rg = 0; rg < 4; ++rg) {
          const int keyloc = kt * 16 + sg * 4 + rg;
          const bool ok = (unsigned)(keyloc - qcol + 3) <= 6u;
          const float v = ok ? st[kt][rg] * scale2 : -INFINITY;
          st[kt][rg] = v;
          mc = fmaxf(mc, v);
        }
      mc = fmaxf(mc, __shfl_xor(mc, 16));
      mc = fmaxf(mc, __shfl_xor(mc, 32));
      const float mnew = fmaxf(m_run, mc);
      const float alpha = exp2g(m_run - mnew);   // 0 on first chunk
      float lc = 0.f;
      #pragma unroll
      for (int kt = 0; kt < 4; ++kt)
        #pragma unroll
        for (int rg = 0; rg < 4; ++rg) {
          const float e = exp2g(st[kt][rg] - mnew);   // masked -> 0
          st[kt][rg] = e;
          lc += e;
        }
      lc += __shfl_xor(lc, 16);
      lc += __shfl_xor(lc, 32);
      l_run = l_run * alpha + lc;
      m_run = mnew;
      Od[0] *= alpha;
      Od[1] *= alpha;

      // ---- pack p to bf16 pairs, exchange into P B-frags, PV --------------
      unsigned pkw[8];
      #pragma unroll
      for (int kt = 0; kt < 4; ++kt) {
        pkw[kt * 2 + 0] = cvtpk_bf16(st[kt][0], st[kt][1]);
        pkw[kt * 2 + 1] = cvtpk_bf16(st[kt][2], st[kt][3]);
      }
      #pragma unroll
      for (int hf = 0; hf < 2; ++hf) {
        unsigned wA[2], wB[2];
        #pragma unroll
        for (int w2 = 0; w2 < 2; ++w2) {
          const unsigned a0 = (unsigned)__shfl((int)pkw[(2 * hf) * 2 + w2], laA);
          const unsigned a1 = (unsigned)__shfl((int)pkw[(2 * hf + 1) * 2 + w2], laA);
          wA[w2] = hiG ? a1 : a0;
          const unsigned b0 = (unsigned)__shfl((int)pkw[(2 * hf) * 2 + w2], laB);
          const unsigned b1 = (unsigned)__shfl((int)pkw[(2 * hf + 1) * 2 + w2], laB);
          wB[w2] = hiG ? b1 : b0;
        }
        union { unsigned u[4]; bf16x8 v; } pf;
        pf.u[0] = wA[0]; pf.u[1] = wA[1]; pf.u[2] = wB[0]; pf.u[3] = wB[1];
        __builtin_amdgcn_s_setprio(1);
        #pragma unroll
        for (int dt = 0; dt < 2; ++dt) {
          const int d = dt * 16 + q15;
          const int chl = bri * 8 + hf * 4 + sg;
          const bf16x8 vf = *(const bf16x8*)((const char*)Vt + d * 1024 +
                                             ((chl ^ (d & 7)) << 4));
          Od[dt] = __builtin_amdgcn_mfma_f32_16x16x32_bf16(vf, pf.v, Od[dt], 0, 0, 0);
        }
        __builtin_amdgcn_s_setprio(0);
      }
    }
  }

  // ---- normalize + store O^T (lane: d = dt*16+sg*4+rg, q = q15) ------------
  const float invl = 1.0f / l_run;
  #pragma unroll
  for (int dt = 0; dt < 2; ++dt) {
    const unsigned w0 = cvtpk_bf16(Od[dt][0] * invl, Od[dt][1] * invl);
    const unsigned w1 = cvtpk_bf16(Od[dt][2] * invl, Od[dt][3] * invl);
    unsigned short* dst = attn_out + (size_t)(b * 4096 + r * 64 + qcol) * 256 +
                          h * 32 + dt * 16 + sg * 4;
    uint2 uu; uu.x = w0; uu.y = w1;
    *(uint2*)dst = uu;
  }
}

extern "C" void kernel_launch(void* const* d_in, const int* in_sizes, int n_in,
                              void* d_out, int out_size, void* d_ws, size_t ws_size,
                              hipStream_t stream) {
  const float* x     = (const float*)d_in[0];
  const float* Wqkv  = (const float*)d_in[1];
  const float* Wproj = (const float*)d_in[2];
  const float* bproj = (const float*)d_in[3];
  const float* temp  = (const float*)d_in[4];
  float* out = (float*)d_out;

  // workspace layout (bytes):
  //   [0, 12582912)            qkv bf16 planes: 48 x 131072 elems
  //                            (Q/K planes [tok][32]; V planes transposed [32][4096])
  //   [25165824, 29360128)     attn_bf16 [8192][256]
  char* ws = (char*)d_ws;
  unsigned short* qkv_bf  = (unsigned short*)ws;
  __hip_bfloat16* attn_bf = (__hip_bfloat16*)(ws + 25165824);

  // 1) qkv = x @ Wqkv^T (fused fp32->bf16), Q/K planar + V transposed
  {
    dim3 grid(3 * DIM / 128, MTOT / 128);   // (6, 64)
    gemm_qkv<<<grid, 256, 0, stream>>>(x, Wqkv, qkv_bf);
  }
  // 2) MFMA flash-band attention (2 query-rows/block) -> attn_bf
  local_attn_mfma<<<BATCH * NHEAD * (GRD / 2), 512, 0, stream>>>(
      qkv_bf, temp, (unsigned short*)attn_bf);
  // 3) out = attn @ Wproj^T + bias
  {
    dim3 grid(DIM / 128, MTOT / 64);        // (2, 128) = 256 blocks
    gemm_proj<<<grid, 256, 0, stream>>>(attn_bf, Wproj, bproj, out);
  }
}